// Round 12
// baseline (1902.368 us; speedup 1.0000x reference)
//
#include <hip/hip_runtime.h>
#include <math.h>

#define HID    128
#define NTREE  6000
#define NGRAPH 144000
#define NNODE  150000
#define NEDGE  600000
#define NSEG   4096
#define AF     34
#define EPSF   1e-8f

#define SCAN_BLK   256
#define SCAN_ELEMS 1024
#define NSCAN ((NNODE + SCAN_ELEMS - 1) / SCAN_ELEMS)   // 147

// ---------------- reductions ----------------

__device__ __forceinline__ float waveReduceSum(float v) {
#pragma unroll
  for (int o = 32; o > 0; o >>= 1) v += __shfl_down(v, o, 64);
  return v;
}

// block of exactly 128 threads (2 waves)
__device__ __forceinline__ float blockReduce128(float v, float* red) {
  v = waveReduceSum(v);
  int w = threadIdx.x >> 6;
  if ((threadIdx.x & 63) == 0) red[w] = v;
  __syncthreads();
  float r = red[0] + red[1];
  __syncthreads();
  return r;
}

// ---------------- CSR build ----------------

__global__ void k_hist(const int* __restrict__ dst, int* __restrict__ deg) {
  int e = blockIdx.x * blockDim.x + threadIdx.x;
  if (e < NEDGE) atomicAdd(&deg[dst[e]], 1);
}

__global__ void k_scan1(const int* __restrict__ deg, int* __restrict__ off,
                        int* __restrict__ part) {
  __shared__ int s[SCAN_BLK];
  int b = blockIdx.x, t = threadIdx.x;
  int base = b * SCAN_ELEMS + t * 4;
  int v0 = 0, v1 = 0, v2 = 0, v3 = 0;
  if (base + 0 < NNODE) v0 = deg[base + 0];
  if (base + 1 < NNODE) v1 = deg[base + 1];
  if (base + 2 < NNODE) v2 = deg[base + 2];
  if (base + 3 < NNODE) v3 = deg[base + 3];
  int sum = v0 + v1 + v2 + v3;
  s[t] = sum;
  __syncthreads();
  for (int o = 1; o < SCAN_BLK; o <<= 1) {
    int x = (t >= o) ? s[t - o] : 0;
    __syncthreads();
    s[t] += x;
    __syncthreads();
  }
  int run = s[t] - sum;  // exclusive prefix for this thread within block
  run += v0; if (base + 0 < NNODE) off[base + 1] = run;
  run += v1; if (base + 1 < NNODE) off[base + 2] = run;
  run += v2; if (base + 2 < NNODE) off[base + 3] = run;
  run += v3; if (base + 3 < NNODE) off[base + 4] = run;
  if (t == SCAN_BLK - 1) part[b] = s[t];
  if (b == 0 && t == 0) off[0] = 0;
}

__global__ void k_scan2(int* part, int nb) {
  __shared__ int s[SCAN_BLK];
  int t = threadIdx.x;
  s[t] = (t < nb) ? part[t] : 0;
  __syncthreads();
  for (int o = 1; o < SCAN_BLK; o <<= 1) {
    int x = (t >= o) ? s[t - o] : 0;
    __syncthreads();
    s[t] += x;
    __syncthreads();
  }
  if (t < nb) part[t] = s[t];
}

__global__ void k_scan3(int* __restrict__ off, const int* __restrict__ part) {
  int b = blockIdx.x;
  if (b == 0) return;
  int add = part[b - 1];
  int base = b * SCAN_ELEMS + threadIdx.x * 4 + 1;
#pragma unroll
  for (int j = 0; j < 4; j++) {
    int idx = base + j;
    if (idx <= NNODE) off[idx] += add;
  }
}

__global__ void k_fill(const int* __restrict__ dst, const int* __restrict__ src,
                       const float* __restrict__ ew, int* __restrict__ cur,
                       int* __restrict__ sperm, float* __restrict__ wperm) {
  int e = blockIdx.x * blockDim.x + threadIdx.x;
  if (e < NEDGE) {
    int d = dst[e];
    int p = atomicAdd(&cur[d], 1);
    sperm[p] = src[e];
    wperm[p] = ew[e];
  }
}

// ---------------- embedding (expmap0 + lorentz_linear W0) ----------------
// Wave-per-row; W0 rows hoisted to VGPRs; readlane broadcasts; single expf.

__global__ __launch_bounds__(256) void k_embed(const float* __restrict__ gfeat,
                                               const float* __restrict__ W0,
                                               const float* __restrict__ b0,
                                               const float* __restrict__ scale0,
                                               float* __restrict__ xout) {
  const int lane = threadIdx.x & 63;
  const int gwave = blockIdx.x * (blockDim.x >> 6) + (threadIdx.x >> 6);
  const int nwaves = gridDim.x * (blockDim.x >> 6);

  float wa[AF + 1], wb[AF + 1];
  {
    const float* ra = W0 + (size_t)lane * (AF + 1);
    const float* rb = W0 + (size_t)(lane + 64) * (AF + 1);
#pragma unroll
    for (int k = 0; k < AF + 1; ++k) { wa[k] = ra[k]; wb[k] = rb[k]; }
  }
  const float ba = b0[lane];
  const float bbv = b0[lane + 64];
  const float escale = expf(scale0[0]);

  for (int g = gwave; g < NGRAPH; g += nwaves) {
    float sv = (lane < AF) ? gfeat[(size_t)g * AF + lane] : 0.f;
    float ss = sv * sv;
#pragma unroll
    for (int m = 1; m <= 32; m <<= 1) ss += __shfl_xor(ss, m, 64);
    float nrm = fmaxf(sqrtf(ss), EPSF);
    float e = expf(nrm);
    float ei = 1.f / e;
    float coshv = 0.5f * (e + ei);
    float sh = 0.5f * (e - ei) / nrm;
    float gs = sh * sv;

    float acc0 = fmaf(wa[0], coshv, ba);
    float acc1 = fmaf(wb[0], coshv, bbv);
#pragma unroll
    for (int k = 1; k < AF + 1; ++k) {
      float gk = __int_as_float(
          __builtin_amdgcn_readlane(__float_as_int(gs), k - 1));
      acc0 = fmaf(wa[k], gk, acc0);
      acc1 = fmaf(wb[k], gk, acc1);
    }
    float part = ((lane == 0) ? 0.f : acc0 * acc0) + acc1 * acc1;
#pragma unroll
    for (int m = 1; m <= 32; m <<= 1) part += __shfl_xor(part, m, 64);
    float y0 = __int_as_float(__builtin_amdgcn_readlane(__float_as_int(acc0), 0));
    float timec = 1.f / (1.f + expf(-y0)) * escale + 1.1f;
    float s = (timec * timec - 1.f) / fmaxf(part, EPSF);
    float sq = sqrtf(s);
    float* orow = xout + (size_t)(NTREE + g) * HID;
    orow[lane] = (lane == 0) ? timec : acc0 * sq;
    orow[lane + 64] = acc1 * sq;
  }
}

// ---------------- lorentz_linear (128x128), W-in-registers f32 ----------------
// Round-9 forensics: the LDS-tiled version is LDS-BANDWIDTH-bound, not
// conflict-bound: 1 B of LDS per FLOP vs ~128 B/cyc LDS and 256 FLOP/cyc VALU
// -> hard 50% VALU ceiling (measured VALUBusy 50.5%). Fix: k_embed pattern
// scaled up. Lane owns output cols (lane, lane+64); W rows for those cols are
// loop-invariant -> hoisted into 256 VGPRs (64 float4). x-row loads are
// wave-uniform (readfirstlane -> scalar/broadcast, L1/L2-served). 4 acc chains
// cover FMA latency (issue slot per chain = 8 cyc >= 4-cyc dep). No LDS at all.
// ~290 VGPR -> 1 wave/SIMD; launch 2048 waves (512 blocks) to fill queue.

template <int RELU>
__global__ __launch_bounds__(256) void k_linear(const float* __restrict__ in,
                                                const float* __restrict__ W,
                                                const float* __restrict__ b,
                                                const float* __restrict__ scale,
                                                float* __restrict__ out) {
  const int lane = threadIdx.x & 63;
  const int wv = (blockIdx.x * blockDim.x + threadIdx.x) >> 6;
  const int nw = (gridDim.x * blockDim.x) >> 6;

  // hoist W rows for cols (lane) and (lane+64): 2 x 128 floats = 64 float4
  float4 wa[32], wb[32];
  {
    const float4* ra = (const float4*)(W + (size_t)lane * HID);
    const float4* rb = (const float4*)(W + (size_t)(lane + 64) * HID);
#pragma unroll
    for (int j = 0; j < 32; ++j) { wa[j] = ra[j]; wb[j] = rb[j]; }
  }
  const float ba = b[lane];
  const float bbv = b[lane + 64];
  const float escale = expf(scale[0]);

  for (int row = wv; row < NNODE; row += nw) {
    const int urow = __builtin_amdgcn_readfirstlane(row);
    const float* xr = in + (size_t)urow * HID;
    float a0 = 0.f, a1 = 0.f, a2 = 0.f, a3 = 0.f;
#pragma unroll
    for (int j = 0; j < 32; j += 2) {
      float4 x0 = *(const float4*)&xr[j * 4];
      float4 x1 = *(const float4*)&xr[j * 4 + 4];
      if (RELU) {
        x0.x = fmaxf(x0.x, 0.f); x0.y = fmaxf(x0.y, 0.f);
        x0.z = fmaxf(x0.z, 0.f); x0.w = fmaxf(x0.w, 0.f);
        x1.x = fmaxf(x1.x, 0.f); x1.y = fmaxf(x1.y, 0.f);
        x1.z = fmaxf(x1.z, 0.f); x1.w = fmaxf(x1.w, 0.f);
      }
      a0 = fmaf(wa[j].x, x0.x, a0);
      a2 = fmaf(wb[j].x, x0.x, a2);
      a1 = fmaf(wa[j + 1].x, x1.x, a1);
      a3 = fmaf(wb[j + 1].x, x1.x, a3);
      a0 = fmaf(wa[j].y, x0.y, a0);
      a2 = fmaf(wb[j].y, x0.y, a2);
      a1 = fmaf(wa[j + 1].y, x1.y, a1);
      a3 = fmaf(wb[j + 1].y, x1.y, a3);
      a0 = fmaf(wa[j].z, x0.z, a0);
      a2 = fmaf(wb[j].z, x0.z, a2);
      a1 = fmaf(wa[j + 1].z, x1.z, a1);
      a3 = fmaf(wb[j + 1].z, x1.z, a3);
      a0 = fmaf(wa[j].w, x0.w, a0);
      a2 = fmaf(wb[j].w, x0.w, a2);
      a1 = fmaf(wa[j + 1].w, x1.w, a1);
      a3 = fmaf(wb[j + 1].w, x1.w, a3);
    }
    float acc0 = ba + a0 + a1;
    float acc1 = bbv + a2 + a3;
    float part = ((lane == 0) ? 0.f : acc0 * acc0) + acc1 * acc1;
#pragma unroll
    for (int m = 1; m <= 32; m <<= 1) part += __shfl_xor(part, m, 64);
    float y0 = __int_as_float(__builtin_amdgcn_readlane(__float_as_int(acc0), 0));
    float timec = 1.f / (1.f + expf(-y0)) * escale + 1.1f;
    float s = (timec * timec - 1.f) / fmaxf(part, EPSF);
    float sq = sqrtf(s);
    float* orow = out + (size_t)row * HID;
    orow[lane] = (lane == 0) ? timec : acc0 * sq;
    orow[lane + 64] = acc1 * sq;
  }
}

// ---------------- CSR gather + fused centroid normalize ----------------

__global__ void k_gather(const float* __restrict__ h, const int* __restrict__ off,
                         const int* __restrict__ sperm, const float* __restrict__ wperm,
                         float* __restrict__ out) {
  __shared__ float red[2];
  int n = blockIdx.x;
  int t = threadIdx.x;
  int e0 = off[n], e1 = off[n + 1];
  float acc = 0.f;
  for (int e = e0; e < e1; ++e) {
    int s = sperm[e];
    float w = wperm[e];
    acc += w * h[(size_t)s * HID + t];
  }
  float part = (t == 0) ? acc * acc : -acc * acc;
  float d = blockReduce128(part, red);
  float denom = sqrtf(fmaxf(fabsf(d), EPSF));
  out[(size_t)n * HID + t] = acc / denom;
}

// ---------------- final segment mean + normalize ----------------

__device__ __forceinline__ int lowerBound(const int* __restrict__ a, int n, int key) {
  int lo = 0, hi = n;
  while (lo < hi) {
    int mid = (lo + hi) >> 1;
    if (a[mid] < key) lo = mid + 1; else hi = mid;
  }
  return lo;
}

__global__ void k_final(const float* __restrict__ h, const int* __restrict__ seg,
                        float* __restrict__ out) {
  __shared__ float red[2];
  int bseg = blockIdx.x;
  int t = threadIdx.x;
  int lo = lowerBound(seg, NGRAPH, bseg);
  int hi = lowerBound(seg, NGRAPH, bseg + 1);
  float acc = 0.f;
  for (int r = lo; r < hi; ++r) acc += h[(size_t)(NTREE + r) * HID + t];
  float cnt = (float)(hi - lo);
  float ave = acc / fmaxf(cnt, 1.f);
  float part = (t == 0) ? ave * ave : -ave * ave;
  float d = blockReduce128(part, red);
  float denom = sqrtf(fmaxf(fabsf(d), EPSF));
  out[bseg * HID + t] = ave / denom;
}

// ---------------- launch ----------------

extern "C" void kernel_launch(void* const* d_in, const int* in_sizes, int n_in,
                              void* d_out, int out_size, void* d_ws, size_t ws_size,
                              hipStream_t stream) {
  const float* gfeat  = (const float*)d_in[0];
  const float* tfeat  = (const float*)d_in[1];
  const float* ew     = (const float*)d_in[2];
  const float* W0     = (const float*)d_in[3];
  const float* b0     = (const float*)d_in[4];
  const float* scale0 = (const float*)d_in[5];
  const float* Wl     = (const float*)d_in[6];
  const float* bl     = (const float*)d_in[7];
  const float* scalel = (const float*)d_in[8];
  const int* esrc     = (const int*)d_in[9];
  const int* edst     = (const int*)d_in[10];
  const int* segids   = (const int*)d_in[11];
  float* outp = (float*)d_out;

  char* ws = (char*)d_ws;
  size_t o = 0;
  auto take = [&](size_t bytes) -> char* {
    char* p = ws + o;
    o = (o + bytes + 255) & ~(size_t)255;
    return p;
  };
  int*   off   = (int*)take((NNODE + 1) * sizeof(int));
  int*   cur   = (int*)take(NNODE * sizeof(int));
  int*   sperm = (int*)take(NEDGE * sizeof(int));
  float* wperm = (float*)take(NEDGE * sizeof(float));
  int*   part  = (int*)take(SCAN_BLK * sizeof(int));
  float* bufA  = (float*)take((size_t)NNODE * HID * sizeof(float));
  float* bufB  = (float*)take((size_t)NNODE * HID * sizeof(float));
  (void)ws_size; (void)in_sizes; (void)n_in; (void)out_size;

  // CSR build (by destination)
  hipMemsetAsync(cur, 0, NNODE * sizeof(int), stream);
  k_hist<<<(NEDGE + 255) / 256, 256, 0, stream>>>(edst, cur);
  k_scan1<<<NSCAN, SCAN_BLK, 0, stream>>>(cur, off, part);
  k_scan2<<<1, SCAN_BLK, 0, stream>>>(part, NSCAN);
  k_scan3<<<NSCAN, SCAN_BLK, 0, stream>>>(off, part);
  hipMemcpyAsync(cur, off, NNODE * sizeof(int), hipMemcpyDeviceToDevice, stream);
  k_fill<<<(NEDGE + 255) / 256, 256, 0, stream>>>(edst, esrc, ew, cur, sperm, wperm);

  // initial node features: tree rows are a straight copy; graph rows computed
  hipMemcpyAsync(bufA, tfeat, (size_t)NTREE * HID * sizeof(float),
                 hipMemcpyDeviceToDevice, stream);
  k_embed<<<1024, 256, 0, stream>>>(gfeat, W0, b0, scale0, bufA);

  // 3 message-passing layers
  for (int i = 0; i < 3; i++) {
    const float* Wi = Wl + (size_t)i * HID * HID;
    const float* bi = bl + (size_t)i * HID;
    const float* si = scalel + i;
    if (i == 0)
      k_linear<0><<<512, 256, 0, stream>>>(bufA, Wi, bi, si, bufB);
    else
      k_linear<1><<<512, 256, 0, stream>>>(bufA, Wi, bi, si, bufB);
    k_gather<<<NNODE, 128, 0, stream>>>(bufB, off, sperm, wperm, bufA);
  }

  // segment mean + normalize
  k_final<<<NSEG, 128, 0, stream>>>(bufA, segids, outp);
}